// Round 5
// baseline (49.536 us; speedup 1.0000x reference)
//
#include <hip/hip_runtime.h>
#include <hip/hip_bf16.h>
#include <math.h>

#define CIN 256
#define COUT 768   // 3 * OUTC
#define OUTC 256
#define HH 64
#define WW 64
#define HW 4096

typedef unsigned int uint32;
typedef unsigned short ushort16;

using short8 = __attribute__((ext_vector_type(8))) short;
using f32x4  = __attribute__((ext_vector_type(4))) float;

// pack 2 fp32 -> 2 bf16 (RTNE) in one dword (a = low 16, b = high 16)
__device__ inline uint32 pkbf2(float a, float b) {
    __hip_bfloat162 h = __float22bfloat162_rn(make_float2(a, b));
    union { __hip_bfloat162 h2; uint32 u; } cv; cv.h2 = h;
    return cv.u;
}

// pack 2 fp32 -> 2 fp16 (RTNE) in one dword
__device__ inline uint32 pkhf2(float a, float b) {
    union { _Float16 h[2]; uint32 u; } cv;
    cv.h[0] = (_Float16)a; cv.h[1] = (_Float16)b;
    return cv.u;
}

__device__ inline float f16lo(uint32 u) {
    union { uint32 u; _Float16 h[2]; } c; c.u = u; return (float)c.h[0];
}
__device__ inline float f16hi(uint32 u) {
    union { uint32 u; _Float16 h[2]; } c; c.u = u; return (float)c.h[1];
}

// lane^1 exchange on the VALU pipe (DPP quad_perm [1,0,3,2])
__device__ inline float dpp_xor1(float x) {
#if __has_builtin(__builtin_amdgcn_update_dpp)
    int i = __builtin_amdgcn_update_dpp(0, __float_as_int(x),
                                        0xB1, 0xF, 0xF, true);
    return __int_as_float(i);
#else
    return __shfl_xor(x, 1, 64);
#endif
}

// async global -> LDS, 16 B per lane (wave-uniform LDS base + lane*16)
__device__ inline void gld16(const void* g, void* l) {
    __builtin_amdgcn_global_load_lds(
        (const __attribute__((address_space(1))) unsigned int*)g,
        (__attribute__((address_space(3))) unsigned int*)l, 16, 0, 0);
}

// ---------------------------------------------------------------------------
// Kernel 0a: transpose-convert x: [n][c][p] fp32 -> xT [n][p][c] bf16.
// 64c x 64p tile via LDS.
// ---------------------------------------------------------------------------
__global__ __launch_bounds__(256) void cvt_x_kernel(
    const float* __restrict__ x, ushort16* __restrict__ xT)
{
    __shared__ float T[64][65];
    const int n  = blockIdx.z;
    const int c0 = blockIdx.y * 64;
    const int p0 = blockIdx.x * 64;
    const int tid = threadIdx.x;
    const int ty = tid >> 4, tx = tid & 15;

    #pragma unroll
    for (int i = 0; i < 4; ++i) {
        float4 v = *(const float4*)&x[((size_t)(n * CIN + c0 + i * 16 + ty)) * HW + p0 + tx * 4];
        T[i * 16 + ty][tx * 4 + 0] = v.x;
        T[i * 16 + ty][tx * 4 + 1] = v.y;
        T[i * 16 + ty][tx * 4 + 2] = v.z;
        T[i * 16 + ty][tx * 4 + 3] = v.w;
    }
    __syncthreads();

    #pragma unroll
    for (int it = 0; it < 2; ++it) {
        const int t  = it * 256 + tid;
        const int pl = t >> 3, oc = t & 7;
        uint32 u0 = pkbf2(T[oc * 8 + 0][pl], T[oc * 8 + 1][pl]);
        uint32 u1 = pkbf2(T[oc * 8 + 2][pl], T[oc * 8 + 3][pl]);
        uint32 u2 = pkbf2(T[oc * 8 + 4][pl], T[oc * 8 + 5][pl]);
        uint32 u3 = pkbf2(T[oc * 8 + 6][pl], T[oc * 8 + 7][pl]);
        *(uint4*)&xT[((size_t)n * HW + p0 + pl) * CIN + c0 + oc * 8] =
            make_uint4(u0, u1, u2, u3);
    }
}

// ---------------------------------------------------------------------------
// Kernel 0b: convert W: [768][256] fp32 -> bf16 (no transpose).
// ---------------------------------------------------------------------------
__global__ __launch_bounds__(256) void cvt_w_kernel(
    const float* __restrict__ wq, ushort16* __restrict__ wb)
{
    const int i = (blockIdx.x * 256 + threadIdx.x) * 8;   // < 196608
    float4 a = *(const float4*)&wq[i];
    float4 b = *(const float4*)&wq[i + 4];
    *(uint4*)&wb[i] = make_uint4(pkbf2(a.x, a.y), pkbf2(a.z, a.w),
                                 pkbf2(b.x, b.y), pkbf2(b.z, b.w));
}

// ---------------------------------------------------------------------------
// Kernel 1: QKV projection, bf16 MFMA, global_load_lds staging (m97-style),
// double-buffered LDS, one barrier per K-step.
// A = wb [768][256], B = xT [n][4096][256], both k-contiguous bf16.
// Output: qkv_f16 [n][slot=d>>5][p][dlow=d&31]
// ---------------------------------------------------------------------------
__global__ __launch_bounds__(256) void qkv_gemm2(
    const ushort16* __restrict__ wb, const ushort16* __restrict__ xT,
    const float* __restrict__ bq, ushort16* __restrict__ qkv)
{
    __shared__ ushort16 As[2][128 * 32];   // [buf][row d][k] 64 B rows
    __shared__ ushort16 Bs[2][128 * 32];   // [buf][row p][k]

    const int n   = blockIdx.z;
    const int d0  = blockIdx.y * 128;
    const int p0  = blockIdx.x * 128;
    const int tid = threadIdx.x;
    const int lane = tid & 63;
    const int wid  = tid >> 6;
    const int wm = wid >> 1, wn = wid & 1;

    // staging: wave wid owns rows [wid*32, wid*32+32); lane l -> row +(l>>2), k-off (l&3)*8
    const int srow = lane >> 2;
    const int skk  = (lane & 3) * 8;
    const ushort16* ag = wb + (size_t)(d0 + wid * 32 + srow) * CIN + skk;
    const ushort16* bg = xT + ((size_t)n * HW + p0 + wid * 32 + srow) * CIN + skk;

    const int lrow = lane & 15;
    const int lk   = (lane >> 4) * 8;

    f32x4 acc[4][4];
    #pragma unroll
    for (int i = 0; i < 4; ++i)
        #pragma unroll
        for (int j = 0; j < 4; ++j) acc[i][j] = (f32x4){0.f, 0.f, 0.f, 0.f};

#define STAGE(buf, ko) do {                                              \
        gld16(ag + (ko),            &As[buf][(wid * 32)      * 32]);     \
        gld16(ag + (ko) + 16 * CIN, &As[buf][(wid * 32 + 16) * 32]);     \
        gld16(bg + (ko),            &Bs[buf][(wid * 32)      * 32]);     \
        gld16(bg + (ko) + 16 * CIN, &Bs[buf][(wid * 32 + 16) * 32]);     \
    } while (0)

    STAGE(0, 0);
    __syncthreads();   // drains vmcnt -> buf0 ready

    int cur = 0;
    #pragma unroll 1
    for (int kt = 0; kt < 8; ++kt) {
        if (kt < 7) STAGE(cur ^ 1, (kt + 1) * 32);   // in flight across compute

        short8 af[4], bf[4];
        #pragma unroll
        for (int fm = 0; fm < 4; ++fm)
            af[fm] = *(const short8*)&As[cur][(wm * 64 + fm * 16 + lrow) * 32 + lk];
        #pragma unroll
        for (int fn = 0; fn < 4; ++fn)
            bf[fn] = *(const short8*)&Bs[cur][(wn * 64 + fn * 16 + lrow) * 32 + lk];
        #pragma unroll
        for (int fm = 0; fm < 4; ++fm)
            #pragma unroll
            for (int fn = 0; fn < 4; ++fn)
                acc[fm][fn] = __builtin_amdgcn_mfma_f32_16x16x32_bf16(
                    af[fm], bf[fn], acc[fm][fn], 0, 0, 0);

        __syncthreads();   // drains vmcnt (next buf ready) + lgkm (cur reads done)
        cur ^= 1;
    }
#undef STAGE

    // epilogue: bias + cvt fp16 + store packed [n][slot][p][dlow]
    const int hi4 = lane >> 4;
    ushort16* qn = qkv + (size_t)n * COUT * HW;
    #pragma unroll
    for (int fm = 0; fm < 4; ++fm) {
        const int D = d0 + wm * 64 + fm * 16 + hi4 * 4;
        const float4 bias = *(const float4*)(&bq[D]);
        const int slot = D >> 5, dlow = D & 31;
        ushort16* qs = qn + (size_t)slot * (HW * 32) + dlow;
        #pragma unroll
        for (int fn = 0; fn < 4; ++fn) {
            const int p = p0 + wn * 64 + fn * 16 + lrow;
            f32x4 v = acc[fm][fn];
            uint32 u0 = pkhf2(v[0] + bias.x, v[1] + bias.y);
            uint32 u1 = pkhf2(v[2] + bias.z, v[3] + bias.w);
            *(uint2*)(qs + (size_t)p * 32) = make_uint2(u0, u1);
        }
    }
}

// ---------------------------------------------------------------------------
// Kernel 2: 5x5 neighborhood attention (UNCHANGED from round 4).
// ---------------------------------------------------------------------------
#define TR 4
#define TC 32
#define HR 8
#define HC 36
#define NPIX (HR*HC)  // 288

__global__ __launch_bounds__(256) void attn_kernel(
    const ushort16* __restrict__ qkv, float* __restrict__ out)
{
    __shared__ uint4 Ks[NPIX * 4];   // 18 KB
    __shared__ uint4 Vs[NPIX * 4];   // 18 KB

    const int n    = blockIdx.z;
    const int head = blockIdx.y;
    const int ht = blockIdx.x >> 1;
    const int wt = blockIdx.x & 1;
    const int h0 = ht * TR;
    const int w0 = wt * TC;

    const int tid  = threadIdx.x;
    const int half = tid & 1;
    const int wc   = (tid >> 1) & 31;
    const int tr   = tid >> 6;

    const int h = h0 + tr, w = w0 + wc;
    const int p = h * WW + w;

    const uint4* Kb = (const uint4*)(qkv + ((size_t)(n * 24 + 8 + head)) * HW * 32);
    const uint4* Vb = (const uint4*)(qkv + ((size_t)(n * 24 + 16 + head)) * HW * 32);

    for (int c = tid; c < 2 * NPIX * 4; c += 256) {
        const int b  = (c >= NPIX * 4);
        const int cc = c - b * NPIX * 4;
        const int pix = cc >> 2, i = cc & 3;
        const int hr = pix / HC, cw = pix - hr * HC;
        const int hh = h0 + hr - 2, ww = w0 + cw - 2;
        if (hh >= 0 && hh < HH && ww >= 0 && ww < WW) {
            const int pp = hh * WW + ww;
            const uint4 v = (b ? Vb : Kb)[(size_t)pp * 4 + i];
            const int unit = (pix * 4 + i) ^ (pix & 7);
            (b ? Vs : Ks)[unit] = v;
        }
    }

    float qf[16];
    {
        const uint4* Qp = (const uint4*)(qkv + (((size_t)(n * 24 + head)) * HW + p) * 32);
        #pragma unroll
        for (int i = 0; i < 2; ++i) {
            uint4 u = Qp[half * 2 + i];
            qf[8*i+0] = f16lo(u.x); qf[8*i+1] = f16hi(u.x);
            qf[8*i+2] = f16lo(u.y); qf[8*i+3] = f16hi(u.y);
            qf[8*i+4] = f16lo(u.z); qf[8*i+5] = f16hi(u.z);
            qf[8*i+6] = f16lo(u.w); qf[8*i+7] = f16hi(u.w);
        }
    }

    __syncthreads();

    float sc[25];
    #pragma unroll
    for (int ky = 0; ky < 5; ++ky) {
        const int hh = h + ky - 2;
        const int hr = tr + ky;
        #pragma unroll
        for (int kx = 0; kx < 5; ++kx) {
            const int ww = w + kx - 2;
            float s;
            if (hh >= 0 && hh < HH && ww >= 0 && ww < WW) {
                const int pix = hr * HC + (wc + kx);
                const int u0 = (pix * 4 + half * 2)     ^ (pix & 7);
                const int u1 = (pix * 4 + half * 2 + 1) ^ (pix & 7);
                uint4 a = Ks[u0], b = Ks[u1];
                float t = 0.f;
                t = fmaf(qf[0],  f16lo(a.x), t); t = fmaf(qf[1],  f16hi(a.x), t);
                t = fmaf(qf[2],  f16lo(a.y), t); t = fmaf(qf[3],  f16hi(a.y), t);
                t = fmaf(qf[4],  f16lo(a.z), t); t = fmaf(qf[5],  f16hi(a.z), t);
                t = fmaf(qf[6],  f16lo(a.w), t); t = fmaf(qf[7],  f16hi(a.w), t);
                t = fmaf(qf[8],  f16lo(b.x), t); t = fmaf(qf[9],  f16hi(b.x), t);
                t = fmaf(qf[10], f16lo(b.y), t); t = fmaf(qf[11], f16hi(b.y), t);
                t = fmaf(qf[12], f16lo(b.z), t); t = fmaf(qf[13], f16hi(b.z), t);
                t = fmaf(qf[14], f16lo(b.w), t); t = fmaf(qf[15], f16hi(b.w), t);
                s = t;
            } else {
                s = -1e30f;
            }
            sc[ky * 5 + kx] = s;
        }
    }
    #pragma unroll
    for (int k = 0; k < 25; ++k) {
        float o = dpp_xor1(sc[k]);
        sc[k] = (sc[k] <= -1e29f) ? sc[k] : sc[k] + o;
    }

    float m = sc[0];
    #pragma unroll
    for (int k = 1; k < 25; ++k) m = fmaxf(m, sc[k]);
    float sum = 0.f;
    #pragma unroll
    for (int k = 0; k < 25; ++k) {
        float e = __expf(sc[k] - m);
        sc[k] = e;
        sum += e;
    }
    const float inv = 1.f / sum;

    float al[8], ah[8];
    #pragma unroll
    for (int i = 0; i < 8; ++i) { al[i] = 0.f; ah[i] = 0.f; }
    #pragma unroll
    for (int ky = 0; ky < 5; ++ky) {
        const int hh = h + ky - 2;
        if (hh < 0 || hh >= HH) continue;
        const int hr = tr + ky;
        #pragma unroll
        for (int kx = 0; kx < 5; ++kx) {
            const int ww = w + kx - 2;
            if (ww < 0 || ww >= WW) continue;
            const float a = sc[ky * 5 + kx];
            const int pix = hr * HC + (wc + kx);
            const int u0 = (pix * 4 + half * 2)     ^ (pix & 7);
            const int u1 = (pix * 4 + half * 2 + 1) ^ (pix & 7);
            uint4 x = Vs[u0], y = Vs[u1];
            al[0] = fmaf(a, f16lo(x.x), al[0]); ah[0] = fmaf(a, f16hi(x.x), ah[0]);
            al[1] = fmaf(a, f16lo(x.y), al[1]); ah[1] = fmaf(a, f16hi(x.y), ah[1]);
            al[2] = fmaf(a, f16lo(x.z), al[2]); ah[2] = fmaf(a, f16hi(x.z), ah[2]);
            al[3] = fmaf(a, f16lo(x.w), al[3]); ah[3] = fmaf(a, f16hi(x.w), ah[3]);
            al[4] = fmaf(a, f16lo(y.x), al[4]); ah[4] = fmaf(a, f16hi(y.x), ah[4]);
            al[5] = fmaf(a, f16lo(y.y), al[5]); ah[5] = fmaf(a, f16hi(y.y), ah[5]);
            al[6] = fmaf(a, f16lo(y.z), al[6]); ah[6] = fmaf(a, f16hi(y.z), ah[6]);
            al[7] = fmaf(a, f16lo(y.w), al[7]); ah[7] = fmaf(a, f16hi(y.w), ah[7]);
        }
    }

    float* Ob = out + ((size_t)(n * 8 + head) * 32 + half * 16) * HW + p;
    #pragma unroll
    for (int i = 0; i < 8; ++i) {
        Ob[(size_t)(2*i)   * HW] = al[i] * inv;
        Ob[(size_t)(2*i+1) * HW] = ah[i] * inv;
    }
}

// ---------------------------------------------------------------------------
extern "C" void kernel_launch(void* const* d_in, const int* in_sizes, int n_in,
                              void* d_out, int out_size, void* d_ws, size_t ws_size,
                              hipStream_t stream) {
    const float* x  = (const float*)d_in[0];   // (4, 256, 64, 64)
    const float* wq = (const float*)d_in[1];   // (768, 256)
    const float* bq = (const float*)d_in[2];   // (768,)
    float* out = (float*)d_out;                // (4, 256, 64, 64) fp32

    ushort16* qkv = (ushort16*)d_ws;                          // 25.2 MB (fp16 packed)
    ushort16* xT  = (ushort16*)((char*)d_ws + (32u << 20));   // 8.4 MB  (bf16 [n][p][c])
    ushort16* wbf = (ushort16*)((char*)d_ws + (44u << 20));   // 0.4 MB  (bf16 [d][c])

    dim3 g0(HW / 64, CIN / 64, 4);             // (64, 4, 4)
    cvt_x_kernel<<<g0, 256, 0, stream>>>(x, xT);
    cvt_w_kernel<<<96, 256, 0, stream>>>(wq, wbf);

    dim3 g1(HW / 128, COUT / 128, 4);          // (32, 6, 4)
    qkv_gemm2<<<g1, 256, 0, stream>>>(wbf, xT, bq, qkv);

    dim3 g2(32, 8, 4);                         // (16 h-tiles x 2 w-tiles, 8 heads, 4 n)
    attn_kernel<<<g2, 256, 0, stream>>>(qkv, out);
}